// Round 9
// baseline (266.769 us; speedup 1.0000x reference)
//
#include <hip/hip_runtime.h>
#include <math.h>

// Problem constants (fixed by reference)
constexpr int Bn = 4, Ln = 2048, DM = 512, NH = 8, DKv = 32, INNER = 256;
constexpr int TTOK = Bn * Ln;                              // 8192 tokens
constexpr size_t HEAD_ELEMS = (size_t)Bn * NH * Ln * DKv;  // 2,097,152 elems per Q/K/V

// Workspace layout (shorts):
//  [0,2M)   Qh bf16 [n,h,l,d]  (PRE-SCALED by log2(e)/sqrt(32))
//  [2M,4M)  Kh bf16 [n,h,l,d]
//  [4M,6M)  Vt bf16 [n,h,d,l]
//  [6M,8M)  O2b bf16 [tok][256]
//  [8M,12.2M)  Xb bf16 [tok][512]
//  [12.25M, +393216)  Wb bf16 (Wq|Wk|Wv)
//  [+131072]          Wfcb bf16

typedef short short8 __attribute__((ext_vector_type(8)));   // 8 bf16 (4 VGPRs)
typedef short short4v __attribute__((ext_vector_type(4)));  // 4 bf16 (2 VGPRs)
typedef float floatx4 __attribute__((ext_vector_type(4)));  // 16x16 MFMA C/D frag
typedef float floatx16 __attribute__((ext_vector_type(16))); // 32x32 MFMA C/D frag

constexpr size_t XB_OFF  = 8u * 1024 * 1024;        // shorts
constexpr size_t WB_OFF  = 12536832;                // shorts, 16B aligned
constexpr size_t WFCB_OFF = WB_OFF + 3 * 131072;

constexpr float C1 = 0.25505654f;  // log2(e)/sqrt(32), folded into Qh at projection

__device__ inline short f2bf(float x) {                     // RNE f32->bf16
  unsigned u = __builtin_bit_cast(unsigned, x);
  unsigned r = (u + 0x7FFFu + ((u >> 16) & 1u)) >> 16;
  return (short)r;
}

// ---------------- Weight pre-convert: fp32 -> bf16 ----------------
__global__ __launch_bounds__(256) void cvtw_kernel(
    const float* __restrict__ Wq, const float* __restrict__ Wk,
    const float* __restrict__ Wv, const float* __restrict__ Wfc,
    short* __restrict__ Wb, short* __restrict__ Wfcb)
{
  const int z = blockIdx.y;
  const float* src = z == 0 ? Wq : (z == 1 ? Wk : (z == 2 ? Wv : Wfc));
  short* dst = z < 3 ? Wb + (size_t)z * 131072 : Wfcb;
  const int idx = (blockIdx.x * 256 + threadIdx.x) * 4;   // 131072 elems, grid.x=128
  float4 x = *(const float4*)&src[idx];
  *(short4v*)&dst[idx] = (short4v){f2bf(x.x), f2bf(x.y), f2bf(x.z), f2bf(x.w)};
}

// ---------------- Projection (bf16 MFMA): X staged in LDS, W frags direct from L2 ----------------
// grid (TTOK/64, INNER/64, 3), block 256 = 4 waves. Q output pre-scaled by C1.
__global__ __launch_bounds__(256) void proj_kernel(
    const float* __restrict__ q, const float* __restrict__ k, const float* __restrict__ v,
    const short* __restrict__ Wb,
    const float* __restrict__ bq, const float* __restrict__ bk,
    const float* __restrict__ bv,
    short* __restrict__ ws)
{
  const int mat = blockIdx.z;
  const float* X    = mat == 0 ? q  : (mat == 1 ? k  : v);
  const short* W    = Wb + (size_t)mat * 131072;
  const float* bias = mat == 0 ? bq : (mat == 1 ? bk : bv);
  short* outp = ws + (size_t)mat * HEAD_ELEMS;

  const int t0 = blockIdx.x * 64;
  const int c0 = blockIdx.y * 64;
  const int tid = threadIdx.x;
  const int col = tid & 15;
  const int quad = (tid & 63) >> 4;
  const int w = tid >> 6;

  __shared__ short Xs[64 * 136];

  floatx4 acc[4];
#pragma unroll
  for (int nj = 0; nj < 4; ++nj) acc[nj] = (floatx4){0.f, 0.f, 0.f, 0.f};

  float4 xr[8];
  auto loadX = [&](int k0) {
#pragma unroll
    for (int j = 0; j < 8; ++j) {
      const int i = tid + j * 256, row = i >> 5, c4 = i & 31;
      xr[j] = *(const float4*)&X[(size_t)(t0 + row) * DM + k0 + c4 * 4];
    }
  };

  loadX(0);

  for (int kc = 0; kc < 4; ++kc) {
#pragma unroll
    for (int j = 0; j < 8; ++j) {
      const int i = tid + j * 256, row = i >> 5, c4 = i & 31;
      *(short4v*)&Xs[row * 136 + c4 * 4] =
          (short4v){f2bf(xr[j].x), f2bf(xr[j].y), f2bf(xr[j].z), f2bf(xr[j].w)};
    }
    __syncthreads();
    if (kc < 3) loadX((kc + 1) * 128);   // prefetch next chunk while MFMAs run
#pragma unroll
    for (int ks = 0; ks < 4; ++ks) {
      short8 a = *(const short8*)&Xs[(w * 16 + col) * 136 + ks * 32 + quad * 8];
#pragma unroll
      for (int nj = 0; nj < 4; ++nj) {
        short8 b = *(const short8*)&W[(size_t)(c0 + nj * 16 + col) * DM +
                                      kc * 128 + ks * 32 + quad * 8];
        acc[nj] = __builtin_amdgcn_mfma_f32_16x16x32_bf16(a, b, acc[nj], 0, 0, 0);
      }
    }
    __syncthreads();
  }

#pragma unroll
  for (int nj = 0; nj < 4; ++nj) {
#pragma unroll
    for (int r = 0; r < 4; ++r) {
      const int t = t0 + w * 16 + quad * 4 + r;
      const int n = t >> 11, ll = t & (Ln - 1);
      const int c = c0 + nj * 16 + col;
      const int d = c >> 3, h = c & 7;           // head is FASTEST dim of proj col
      float pv = acc[nj][r] + bias[c];
      if (mat == 0) pv *= C1;                    // fold softmax scale into Q
      const short val = f2bf(pv);
      if (mat < 2)
        outp[((size_t)(n * NH + h) * Ln + ll) * DKv + d] = val;   // [n,h,l,d]
      else
        outp[((size_t)(n * NH + h) * DKv + d) * Ln + ll] = val;   // [n,h,d,l]
    }
  }
}

// ---------------- Attention: single-wave 32x32 MFMA flash, no inter-wave barriers ----------------
// grid 2048 x 64 threads. Flat id = qt*32 + bh (bh fastest -> same head pinned to one XCD,
// K/V L2-hot). One wave owns 32 q over all 2048 keys in 64-key chunks; single-buffered LDS
// (safe: one wave, in-order DS pipe) + register prefetch. MFMA layout math (key bit2<->bit3
// staging perm, St->B-frag pack, ones-MFMA rowsum, epilogue d-map) verbatim from R8
// (harness-verified).
__global__ __launch_bounds__(64, 2) void attn_kernel(const short* __restrict__ ws,
                                                     short* __restrict__ O2b)
{
  const int id = blockIdx.x;
  const int bh = id & 31;
  const int qt = id >> 5;
  const int n = bh >> 3, h = bh & 7;
  const int lane = threadIdx.x;
  const int col = lane & 31;        // q (and m) index
  const int hf = lane >> 5;         // k-slot half
  const int qi = qt * 32 + col;     // this lane's q row

  const short* Qh = ws;
  const short* Kg = ws + HEAD_ELEMS + (size_t)bh * Ln * DKv;      // [l][d]
  const short* Vg = ws + 2 * HEAD_ELEMS + (size_t)bh * DKv * Ln;  // [d][l]

  __shared__ short Ks[64 * 40];   // [perm key][d], pitch 40
  __shared__ short Vs[32 * 72];   // [d][key natural], pitch 72

  // Q as B-frags (pre-scaled by C1): B[k=d=c*16+8*hf+j][n=q=col]
  short8 aq[2];
#pragma unroll
  for (int c = 0; c < 2; ++c)
    aq[c] = *(const short8*)&Qh[(size_t)bh * Ln * DKv + (size_t)qi * DKv + c * 16 + hf * 8];

  short8 ones;
#pragma unroll
  for (int j = 0; j < 8; ++j) ones[j] = (short)0x3F80;  // bf16 1.0

  floatx16 o, ol;
#pragma unroll
  for (int i = 0; i < 16; ++i) { o[i] = 0.f; ol[i] = 0.f; }

  // staging addresses: K row = lane (64B/lane, dense); perm on the LDS write side
  const int permrow = (lane & ~12) | ((lane & 4) << 1) | ((lane & 8) >> 1);
  const int vrow = lane >> 1, vhalf = lane & 1;   // V: row d=lane>>1, key-half lane&1

  short8 krg[4], vrg[4];
#pragma unroll
  for (int j = 0; j < 4; ++j) {
    krg[j] = *(const short8*)(Kg + (size_t)lane * 32 + j * 8);
    vrg[j] = *(const short8*)(Vg + (size_t)vrow * Ln + vhalf * 32 + j * 8);
  }

  for (int kt = 0; kt < 32; ++kt) {
#pragma unroll
    for (int j = 0; j < 4; ++j) {
      *(short8*)&Ks[permrow * 40 + j * 8] = krg[j];
      *(short8*)&Vs[vrow * 72 + vhalf * 32 + j * 8] = vrg[j];
    }
    __syncthreads();                 // 1-wave barrier: just a waitcnt, no convoy
    if (kt < 31) {                   // register prefetch of next 64-key chunk
#pragma unroll
      for (int j = 0; j < 4; ++j) {
        krg[j] = *(const short8*)(Kg + (size_t)(kt + 1) * 2048 + (size_t)lane * 32 + j * 8);
        vrg[j] = *(const short8*)(Vg + (size_t)vrow * Ln + (kt + 1) * 64 + vhalf * 32 + j * 8);
      }
    }

#pragma unroll
    for (int cc = 0; cc < 2; ++cc) {    // 32-key sub-chunks
      // St = K·Q^T  (A rows = permuted-key LDS rows; contraction over d=32)
      floatx16 st;
#pragma unroll
      for (int i = 0; i < 16; ++i) st[i] = 0.f;
      short8 kf0 = *(const short8*)&Ks[(cc * 32 + col) * 40 + hf * 8];
      short8 kf1 = *(const short8*)&Ks[(cc * 32 + col) * 40 + 16 + hf * 8];
      st = __builtin_amdgcn_mfma_f32_32x32x16_bf16(kf0, aq[0], st, 0, 0, 0);
      st = __builtin_amdgcn_mfma_f32_32x32x16_bf16(kf1, aq[1], st, 0, 0, 0);

      // p = exp2(st) (already log2-scaled); pack regs 0..7 / 8..15 -> B-frags
      float p[16];
#pragma unroll
      for (int i = 0; i < 16; ++i) p[i] = __builtin_amdgcn_exp2f(st[i]);
      short8 pf[2];
#pragma unroll
      for (int half = 0; half < 2; ++half) {
        unsigned u[4];
#pragma unroll
        for (int j = 0; j < 4; ++j)
          u[j] = __builtin_amdgcn_perm(
              __builtin_bit_cast(unsigned, p[half * 8 + 2 * j + 1]),
              __builtin_bit_cast(unsigned, p[half * 8 + 2 * j]), 0x07060302u);
        uint4 uu = make_uint4(u[0], u[1], u[2], u[3]);
        pf[half] = __builtin_bit_cast(short8, uu);
      }

      // l += ones^T · P  (all D rows identical = per-q row-sum, on the MFMA pipe)
      ol = __builtin_amdgcn_mfma_f32_32x32x16_bf16(ones, pf[0], ol, 0, 0, 0);
      ol = __builtin_amdgcn_mfma_f32_32x32x16_bf16(ones, pf[1], ol, 0, 0, 0);

      // O^T += V^T · P  (A = V natural key order)
      short8 va0 = *(const short8*)&Vs[col * 72 + cc * 32 + hf * 8];
      short8 va1 = *(const short8*)&Vs[col * 72 + cc * 32 + 16 + hf * 8];
      o = __builtin_amdgcn_mfma_f32_32x32x16_bf16(va0, pf[0], o, 0, 0, 0);
      o = __builtin_amdgcn_mfma_f32_32x32x16_bf16(va1, pf[1], o, 0, 0, 0);
    }
    __syncthreads();                 // reads done before next chunk's stores (1-wave: cheap)
  }

  // epilogue: l = any ol reg; normalize; write O^T
  const float inv = 1.f / ol[0];
  short* dst = &O2b[((size_t)n * Ln + qi) * INNER + h * DKv];
#pragma unroll
  for (int g4 = 0; g4 < 4; ++g4) {      // regs 4g4..4g4+3 -> d = 8*g4 + 4*hf + (0..3)
    short4v pk = (short4v){f2bf(o[g4 * 4 + 0] * inv), f2bf(o[g4 * 4 + 1] * inv),
                           f2bf(o[g4 * 4 + 2] * inv), f2bf(o[g4 * 4 + 3] * inv)};
    *(short4v*)&dst[8 * g4 + 4 * hf] = pk;
  }
}

// ---------------- FC (bf16 MFMA, zero-LDS): Xb = bf16(O2b @ Wfc^T + bfc + q) ----------------
// grid (TTOK/64, DM/64), block 256 = 4 waves. A/B frags loaded directly from global
// (O2b and Wfcb are L2/L3-resident); no staging, no barriers -> latency hidden by occupancy.
__global__ __launch_bounds__(256) void fc_kernel(
    const short* __restrict__ O2b, const short* __restrict__ Wfcb,
    const float* __restrict__ bfc, const float* __restrict__ qin,
    short* __restrict__ Xb)
{
  const int t0 = blockIdx.x * 64;
  const int c0 = blockIdx.y * 64;
  const int tid = threadIdx.x;
  const int col = tid & 15;
  const int quad = (tid & 63) >> 4;
  const int w = tid >> 6;

  floatx4 acc[4];
#pragma unroll
  for (int nj = 0; nj < 4; ++nj) acc[nj] = (floatx4){0.f, 0.f, 0.f, 0.f};

  const short* arow = &O2b[(size_t)(t0 + w * 16 + col) * INNER + quad * 8];
#pragma unroll
  for (int ks = 0; ks < 8; ++ks) {
    short8 a = *(const short8*)&arow[ks * 32];
#pragma unroll
    for (int nj = 0; nj < 4; ++nj) {
      short8 b = *(const short8*)&Wfcb[(size_t)(c0 + nj * 16 + col) * INNER +
                                       ks * 32 + quad * 8];
      acc[nj] = __builtin_amdgcn_mfma_f32_16x16x32_bf16(a, b, acc[nj], 0, 0, 0);
    }
  }

#pragma unroll
  for (int nj = 0; nj < 4; ++nj) {
#pragma unroll
    for (int r = 0; r < 4; ++r) {
      const int t = t0 + w * 16 + quad * 4 + r;
      const int c = c0 + nj * 16 + col;
      Xb[(size_t)t * DM + c] = f2bf(acc[nj][r] + bfc[c] + qin[(size_t)t * DM + c]);
    }
  }
}

// ---------------- LayerNorm over bf16 Xb rows -> fp32 out ----------------
__global__ __launch_bounds__(256) void ln_kernel(
    const short* __restrict__ Xb, const float* __restrict__ gamma,
    const float* __restrict__ beta, float* __restrict__ outp)
{
  const int t = blockIdx.x * 4 + (threadIdx.x >> 6);
  const int lane = threadIdx.x & 63;

  short8 xs = *(const short8*)&Xb[(size_t)t * DM + lane * 8];
  float x[8];
#pragma unroll
  for (int j = 0; j < 8; ++j)
    x[j] = __builtin_bit_cast(float, ((unsigned)(unsigned short)xs[j]) << 16);

  float s1 = 0.f, s2 = 0.f;
#pragma unroll
  for (int j = 0; j < 8; ++j) { s1 += x[j]; s2 += x[j] * x[j]; }
#pragma unroll
  for (int off = 32; off >= 1; off >>= 1) {
    s1 += __shfl_xor(s1, off);
    s2 += __shfl_xor(s2, off);
  }
  const float mean = s1 * (1.f / 512.f);
  const float var = s2 * (1.f / 512.f) - mean * mean;
  const float rstd = rsqrtf(var + 1e-5f);

  float4 g0 = *(const float4*)&gamma[lane * 8];
  float4 g1 = *(const float4*)&gamma[lane * 8 + 4];
  float4 b0 = *(const float4*)&beta[lane * 8];
  float4 b1 = *(const float4*)&beta[lane * 8 + 4];

  float4 y0, y1;
  y0.x = g0.x * (x[0] - mean) * rstd + b0.x;
  y0.y = g0.y * (x[1] - mean) * rstd + b0.y;
  y0.z = g0.z * (x[2] - mean) * rstd + b0.z;
  y0.w = g0.w * (x[3] - mean) * rstd + b0.w;
  y1.x = g1.x * (x[4] - mean) * rstd + b1.x;
  y1.y = g1.y * (x[5] - mean) * rstd + b1.y;
  y1.z = g1.z * (x[6] - mean) * rstd + b1.z;
  y1.w = g1.w * (x[7] - mean) * rstd + b1.w;

  float* drow = &outp[(size_t)t * DM + lane * 8];
  *(float4*)&drow[0] = y0;
  *(float4*)&drow[4] = y1;
}

extern "C" void kernel_launch(void* const* d_in, const int* in_sizes, int n_in,
                              void* d_out, int out_size, void* d_ws, size_t ws_size,
                              hipStream_t stream) {
  const float* q     = (const float*)d_in[0];
  const float* k     = (const float*)d_in[1];
  const float* v     = (const float*)d_in[2];
  const float* Wq    = (const float*)d_in[3];
  const float* bq    = (const float*)d_in[4];
  const float* Wk    = (const float*)d_in[5];
  const float* bk    = (const float*)d_in[6];
  const float* Wv    = (const float*)d_in[7];
  const float* bv    = (const float*)d_in[8];
  const float* Wfc   = (const float*)d_in[9];
  const float* bfc   = (const float*)d_in[10];
  const float* gamma = (const float*)d_in[11];
  const float* beta  = (const float*)d_in[12];

  short* wsS  = (short*)d_ws;
  short* O2b  = wsS + 3 * HEAD_ELEMS;
  short* Xb   = wsS + XB_OFF;
  short* Wb   = wsS + WB_OFF;
  short* Wfcb = wsS + WFCB_OFF;

  cvtw_kernel<<<dim3(128, 4), 256, 0, stream>>>(Wq, Wk, Wv, Wfc, Wb, Wfcb);

  dim3 gp(TTOK / 64, INNER / 64, 3);
  proj_kernel<<<gp, 256, 0, stream>>>(q, k, v, Wb, bq, bk, bv, wsS);

  attn_kernel<<<2048, 64, 0, stream>>>(wsS, O2b);

  dim3 gfc(TTOK / 64, DM / 64);
  fc_kernel<<<gfc, 256, 0, stream>>>(O2b, Wfcb, bfc, q, Xb);

  ln_kernel<<<TTOK / 4, 256, 0, stream>>>(Xb, gamma, beta, (float*)d_out);
}